// Round 3
// baseline (363.381 us; speedup 1.0000x reference)
//
#include <hip/hip_runtime.h>

#define LOG2E 1.4426950408889634f
#define LN2   0.6931471805599453f

__device__ __forceinline__ float x2(float x)  { return __builtin_amdgcn_exp2f(x); }
__device__ __forceinline__ float lg2(float x) { return __builtin_amdgcn_logf(x); }

// DPP wave_shr:1 — lane i <- lane i-1, VALU-local (no LDS pipe, no lgkmcnt).
// Lane 0 gets 0 (old operand); callers never consume lane 0's result.
__device__ __forceinline__ float dpp_shr1_f(float x) {
    return __int_as_float(
        __builtin_amdgcn_update_dpp(0, __float_as_int(x), 0x138, 0xf, 0xf, false));
}
__device__ __forceinline__ int dpp_shr1_i(int x) {
    return __builtin_amdgcn_update_dpp(0, x, 0x138, 0xf, 0xf, false);
}

// async global->LDS DMA (wave-uniform base, lane*size scatter)
#define GLLDS(g, l, sz)                                                    \
    __builtin_amdgcn_global_load_lds(                                      \
        (const __attribute__((address_space(1))) void*)(g),                \
        (__attribute__((address_space(3))) void*)(l), (sz), 0, 0)

// Phase 1: per-(b,t) softmax normalizer + gather token PROBABILITIES into
// pair-major emA (float4/lane: labels 2i,2i+1 at par0 then par1) and a
// compact blank stream emB[b*T + t]. One wave per row, no LDS, no barriers.
__global__ __launch_bounds__(256) void emit_kernel(const float* __restrict__ pred,
                                                   const int* __restrict__ target,
                                                   float* __restrict__ emA,
                                                   float* __restrict__ emB,
                                                   int T, int V, int L) {
    int wave = threadIdx.x >> 6;
    int lane = threadIdx.x & 63;
    int row = blockIdx.x * 4 + wave;            // row = b*T + t
    const float* rowp = pred + (size_t)row * V;
    int nq = V >> 2;                            // 250 float4s
    float4 v0, v1, v2, v3;
    const float4 fill = make_float4(-3.0e38f, -3.0e38f, -3.0e38f, -3.0e38f);
    v0 = (lane       < nq) ? ((const float4*)rowp)[lane]       : fill;
    v1 = (lane + 64  < nq) ? ((const float4*)rowp)[lane + 64]  : fill;
    v2 = (lane + 128 < nq) ? ((const float4*)rowp)[lane + 128] : fill;
    v3 = (lane + 192 < nq) ? ((const float4*)rowp)[lane + 192] : fill;
    float lm = fmaxf(fmaxf(fmaxf(v0.x, v0.y), fmaxf(v0.z, v0.w)),
               fmaxf(fmaxf(fmaxf(v1.x, v1.y), fmaxf(v1.z, v1.w)),
               fmaxf(fmaxf(fmaxf(v2.x, v2.y), fmaxf(v2.z, v2.w)),
                     fmaxf(fmaxf(v3.x, v3.y), fmaxf(v3.z, v3.w)))));
    #pragma unroll
    for (int off = 32; off > 0; off >>= 1) lm = fmaxf(lm, __shfl_xor(lm, off));
    float mm = lm * LOG2E;                      // row max in log2 units
    float ls = 0.f;
    if (lane < nq)
        ls += x2(fmaf(v0.x, LOG2E, -mm)) + x2(fmaf(v0.y, LOG2E, -mm))
            + x2(fmaf(v0.z, LOG2E, -mm)) + x2(fmaf(v0.w, LOG2E, -mm));
    if (lane + 64 < nq)
        ls += x2(fmaf(v1.x, LOG2E, -mm)) + x2(fmaf(v1.y, LOG2E, -mm))
            + x2(fmaf(v1.z, LOG2E, -mm)) + x2(fmaf(v1.w, LOG2E, -mm));
    if (lane + 128 < nq)
        ls += x2(fmaf(v2.x, LOG2E, -mm)) + x2(fmaf(v2.y, LOG2E, -mm))
            + x2(fmaf(v2.z, LOG2E, -mm)) + x2(fmaf(v2.w, LOG2E, -mm));
    if (lane + 192 < nq)
        ls += x2(fmaf(v3.x, LOG2E, -mm)) + x2(fmaf(v3.y, LOG2E, -mm))
            + x2(fmaf(v3.z, LOG2E, -mm)) + x2(fmaf(v3.w, LOG2E, -mm));
    #pragma unroll
    for (int off = 32; off > 0; off >>= 1) ls += __shfl_xor(ls, off);
    float n2 = mm + lg2(ls);                    // log2 normalizer

    int b = row / T;
    int t = row - b * T;
    int p = t >> 1, par = t & 1;
    const int* tg = target + b * L;
    float* arow = emA + ((size_t)b * (T >> 1) + p) * 256;
    for (int j = lane; j < L; j += 64) {
        int tok = tg[j];
        arow[(j >> 1) * 4 + par * 2 + (j & 1)] = x2(fmaf(rowp[tok], LOG2E, -n2));
    }
    float blank_logit = __shfl(v0.x, 0);        // pred[row][0] (token 0)
    if (lane == 0) emB[row] = x2(fmaf(blank_logit, LOG2E, -n2));
}

// Per-batch-element DP state: stored = true * 2^K per lane (linear domain
// with per-lane block exponent).
struct DP {
    float a0, a1, a2, a3;   // 4 extended-label states per lane
    float s1;               // state s=1 (first blank)
    float star_st;          // start-star stored value (lane 0 only)
    float S;                // running sum of alpha_t[ll]+alpha_t[lb]
    float sbase;            // 1.0 on lane 0 else 0
    int   K;                // block exponent
    bool  act;              // lane has been reached
    bool  skipAn;           // right neighbor's skip flag
    bool  skipB;            // within-lane skip (s+2 path)
    bool  slot0;            // ll,lb live in (a0,a1) vs (a2,a3)
    int   lane_e;           // lane holding ll,lb
};

// One DP step. Neighbor value via DPP wave_shr1 (VALU-local); zero
// transcendentals, zero LDS on the dependence chain.
__device__ __forceinline__ void dp_step(DP& d, float ex0, float ex1, float eb,
                                        int lane) {
    float r  = d.a3 + d.a2;
    float q  = d.a1 + d.a0;
    float w  = d.skipAn ? r : d.a3;   // value my RIGHT neighbor needs
    float ur = dpp_shr1_f(w);
    int   Kp = dpp_shr1_i(d.K);
    d.K = d.act ? d.K : Kp;
    float uc = ldexpf(ur, d.K - Kp);
    float sb = d.s1 + d.star_st;
    if (lane == 0) uc = sb;
    d.S += d.slot0 ? q : r;
    d.a2 = ex1 * (d.a2 + (d.skipB ? q : d.a1));
    d.a0 = ex0 * (d.a0 + uc);
    d.a1 = eb * q;
    d.a3 = eb * r;
    d.s1 = eb * sb;
    d.act = d.act || (uc > 0.0f);
}

// Per-lane renorm: rescale stored values so lane max ~ 1, fold into K.
__device__ __forceinline__ void dp_renorm(DP& d) {
    float m4 = fmaxf(fmaxf(d.a0, d.a1), fmaxf(d.a2, d.a3));
    int e = (int)((__float_as_uint(m4) >> 23) & 255u) - 127;
    int dd = d.act ? -e : 0;
    float sc = ldexpf(1.0f, dd);
    d.a0 *= sc; d.a1 *= sc; d.a2 *= sc; d.a3 *= sc; d.s1 *= sc; d.S *= sc;
    d.K += dd;
    d.star_st = ldexpf(d.sbase, d.K);
}

#define BATCH 12   // pairs per LDS staging batch PER batch-element

// Phase 2: barrier-free single-wave W-CTC DP, TWO batch elements per wave
// interleaved. The serial dependence chain of one element leaves ~70% of
// issue slots empty (232 cy/step at ~33 VALU ops); the second, independent
// chain fills them. Emissions double-buffered in LDS via global_load_lds
// with COUNTED vmcnt(26) waits (one 26-load batch-group stays in flight;
// never a fresh-issue drain in the main loop).
__global__ __launch_bounds__(64, 1) void dp_kernel(const float* __restrict__ emA,
                                                   const float* __restrict__ emB,
                                                   const int* __restrict__ target,
                                                   const int* __restrict__ tlen,
                                                   float* __restrict__ nll,
                                                   int T, int L, int B) {
    __shared__ float4 sA[2][2][BATCH][64];   // [buf][bi][pair][lane] 49152 B
    __shared__ float  sB[2][2][64];          // [buf][bi][..] blank rows

    int lane = threadIdx.x;
    int b0 = blockIdx.x * 2;
    int b1i = b0 + 1;
    int b1 = (b1i < B) ? b1i : b0;           // clamp (B is even in practice)
    int NP = T >> 1;
    int NPm1 = NP - 1;
    const float* eA0 = emA + (size_t)b0 * NP * 256;
    const float* eA1 = emA + (size_t)b1 * NP * 256;
    const float* eB0 = emB + (size_t)b0 * T;
    const float* eB1 = emB + (size_t)b1 * T;
    const int* tg0 = target + b0 * L;
    const int* tg1 = target + b1 * L;

    int NPc = NP - 1;                        // pairs 1..NP-1 are staged
    int NB = (NPc + BATCH - 1) / BATCH;

    // ---- prologue scalar loads FIRST (so their waits don't drain batches)
    float4 p0a = ((const float4*)eA0)[lane];
    float4 p0b = ((const float4*)eA1)[lane];
    float be0a = eB0[0], be1a = eB0[1];
    float be0b = eB1[0], be1b = eB1[1];
    int t0a = tg0[2 * lane], t1a = tg0[2 * lane + 1];
    int t0b = tg1[2 * lane], t1b = tg1[2 * lane + 1];
    int tla = tlen[b0], tlb = tlen[b1];

    // issue one batch-group (BATCH pair-rows + 1 blank row, both elements)
    // = 26 vmem loads. ALWAYS 26, so counted vmcnt stays valid; indices
    // clamp so dummy tail issues re-read the last rows (target buf is dead).
    #define ISSUE(c, buf)                                                  \
      do {                                                                 \
        int base_ = 1 + BATCH * (c);                                       \
        _Pragma("unroll")                                                  \
        for (int j_ = 0; j_ < BATCH; ++j_) {                               \
            int pr_ = base_ + j_; if (pr_ > NPm1) pr_ = NPm1;              \
            GLLDS(eA0 + (size_t)pr_ * 256, &sA[buf][0][j_][0], 16);        \
            GLLDS(eA1 + (size_t)pr_ * 256, &sA[buf][1][j_][0], 16);        \
        }                                                                  \
        int bb_ = base_ * 2; if (bb_ > T - 1) bb_ = T - 1;                 \
        GLLDS(eB0 + bb_, &sB[buf][0][0], 4);                               \
        GLLDS(eB1 + bb_, &sB[buf][1][0], 4);                               \
      } while (0)

    ISSUE(0, 0);
    ISSUE(1, 1);

    // ---- per-element init
    DP d0, d1;
    {
        int tprev = __shfl_up(t1a, 1);
        bool skipA = (lane == 0) || (t0a != tprev);
        d0.skipAn = (__shfl_down((int)skipA, 1) != 0);
        d0.skipB = (t1a != t0a);
        int ll = 2 * tla;
        d0.lane_e = (ll - 2) >> 2;
        d0.slot0 = ((ll - 2) & 3) == 0;
        d0.a0 = (lane == 0) ? p0a.x : 0.f;
        d0.a1 = 0.f; d0.a2 = 0.f; d0.a3 = 0.f;
        d0.s1 = (lane == 0) ? be0a : 0.f;
        d0.sbase = (lane == 0) ? 1.0f : 0.0f;
        d0.K = 0; d0.star_st = d0.sbase; d0.act = (lane == 0); d0.S = 0.f;
    }
    {
        int tprev = __shfl_up(t1b, 1);
        bool skipA = (lane == 0) || (t0b != tprev);
        d1.skipAn = (__shfl_down((int)skipA, 1) != 0);
        d1.skipB = (t1b != t0b);
        int ll = 2 * tlb;
        d1.lane_e = (ll - 2) >> 2;
        d1.slot0 = ((ll - 2) & 3) == 0;
        d1.a0 = (lane == 0) ? p0b.x : 0.f;
        d1.a1 = 0.f; d1.a2 = 0.f; d1.a3 = 0.f;
        d1.s1 = (lane == 0) ? be0b : 0.f;
        d1.sbase = (lane == 0) ? 1.0f : 0.0f;
        d1.K = 0; d1.star_st = d1.sbase; d1.act = (lane == 0); d1.S = 0.f;
    }

    // step t=1 from pair 0, parity 1
    dp_step(d0, p0a.z, p0a.w, be1a, lane);
    dp_step(d1, p0b.z, p0b.w, be1b, lane);

    for (int c = 0; c < NB; ++c) {
        // batch c resident when only the one in-flight group (26) remains
        asm volatile("s_waitcnt vmcnt(26)" ::: "memory");
        int buf = c & 1;
        int jn = NPc - BATCH * c; if (jn > BATCH) jn = BATCH;
        float4 e0a = sA[buf][0][0][lane], e0b = sA[buf][1][0][lane];
        float2 h0a = *(const float2*)&sB[buf][0][0];
        float2 h0b = *(const float2*)&sB[buf][1][0];
        float4 e1a = sA[buf][0][1][lane], e1b = sA[buf][1][1][lane];
        float2 h1a = *(const float2*)&sB[buf][0][2];
        float2 h1b = *(const float2*)&sB[buf][1][2];
        for (int j = 0; j < jn; ++j) {
            int j2 = j + 2; if (j2 >= BATCH) j2 -= BATCH;
            float4 e2a = sA[buf][0][j2][lane], e2b = sA[buf][1][j2][lane];
            float2 h2a = *(const float2*)&sB[buf][0][2 * j2];
            float2 h2b = *(const float2*)&sB[buf][1][2 * j2];
            dp_step(d0, e0a.x, e0a.y, h0a.x, lane);
            dp_step(d1, e0b.x, e0b.y, h0b.x, lane);
            dp_step(d0, e0a.z, e0a.w, h0a.y, lane);
            dp_step(d1, e0b.z, e0b.w, h0b.y, lane);
            if (j & 1) { dp_renorm(d0); dp_renorm(d1); }
            e0a = e1a; h0a = h1a; e1a = e2a; h1a = h2a;
            e0b = e1b; h0b = h1b; e1b = e2b; h1b = h2b;
        }
        ISSUE(c + 2, buf);   // always issue (clamped) — keeps vmcnt(26) exact
    }
    #undef ISSUE
    // drain dummy tail issues before LDS teardown at s_endpgm
    asm volatile("s_waitcnt vmcnt(0)" ::: "memory");

    {   // final alpha_{T-1}[ll],[lb] contributions
        float q = d0.a1 + d0.a0, r = d0.a3 + d0.a2;
        d0.S += d0.slot0 ? q : r;
        q = d1.a1 + d1.a0; r = d1.a3 + d1.a2;
        d1.S += d1.slot0 ? q : r;
    }
    float Sv0 = __shfl(d0.S, d0.lane_e);
    int   Kv0 = __shfl(d0.K, d0.lane_e);
    float Sv1 = __shfl(d1.S, d1.lane_e);
    int   Kv1 = __shfl(d1.K, d1.lane_e);
    if (lane == 0) {
        nll[b0] = -((lg2(Sv0) - (float)Kv0) * LN2);
        if (b1i < B) nll[b1i] = -((lg2(Sv1) - (float)Kv1) * LN2);
    }
}

// Phase 3: out = mean_b( nll[b] / tlen[b] )
__global__ __launch_bounds__(64) void fin_kernel(const float* __restrict__ nll,
                                                 const int* __restrict__ tlen,
                                                 float* __restrict__ out, int B) {
    int tid = threadIdx.x;
    float v = (tid < B) ? nll[tid] / (float)tlen[tid] : 0.f;
    #pragma unroll
    for (int off = 32; off > 0; off >>= 1) v += __shfl_xor(v, off);
    if (tid == 0) out[0] = v / (float)B;
}

extern "C" void kernel_launch(void* const* d_in, const int* in_sizes, int n_in,
                              void* d_out, int out_size, void* d_ws, size_t ws_size,
                              hipStream_t stream) {
    const float* pred   = (const float*)d_in[0];
    const int*   target = (const int*)d_in[1];
    const int*   tlen   = (const int*)d_in[2];
    int B = in_sizes[2];
    int L = in_sizes[1] / B;            // 128
    int V = 1000;                       // fixed by the problem
    int T = in_sizes[0] / (B * V);      // 1024

    float* ws  = (float*)d_ws;
    float* nll = ws;                    // 64 floats
    float* emB = ws + 64;               // B*T floats (blank probs, compact)
    float* emA = emB + (size_t)B * T;   // B*(T/2)*256 floats (~16.8 MB)
                                        // (emB precedes emA so the blank
                                        // batch-load's 64-lane over-read on
                                        // the last batch stays inside ws)

    emit_kernel<<<(B * T) / 4, 256, 0, stream>>>(pred, target, emA, emB, T, V, L);
    dp_kernel<<<(B + 1) / 2, 64, 0, stream>>>(emA, emB, target, tlen, nll, T, L, B);
    fin_kernel<<<1, 64, 0, stream>>>(nll, tlen, (float*)d_out, B);
}

// Round 4
// 362.238 us; speedup vs baseline: 1.0032x; 1.0032x over previous
//
#include <hip/hip_runtime.h>

#define LOG2E 1.4426950408889634f
#define LN2   0.6931471805599453f

__device__ __forceinline__ float x2(float x)  { return __builtin_amdgcn_exp2f(x); }
__device__ __forceinline__ float lg2(float x) { return __builtin_amdgcn_logf(x); }

// DPP wave_shr:1 — lane i <- lane i-1, VALU-local (no LDS pipe, no lgkmcnt).
// Lane 0 gets 0 (old operand); callers never consume lane 0's result.
__device__ __forceinline__ float dpp_shr1_f(float x) {
    return __int_as_float(
        __builtin_amdgcn_update_dpp(0, __float_as_int(x), 0x138, 0xf, 0xf, false));
}
__device__ __forceinline__ int dpp_shr1_i(int x) {
    return __builtin_amdgcn_update_dpp(0, x, 0x138, 0xf, 0xf, false);
}

// async global->LDS DMA (wave-uniform base, lane*size scatter)
#define GLLDS(g, l, sz)                                                    \
    __builtin_amdgcn_global_load_lds(                                      \
        (const __attribute__((address_space(1))) void*)(g),                \
        (__attribute__((address_space(3))) void*)(l), (sz), 0, 0)

// Phase 1: per-(b,t) softmax normalizer + gather token PROBABILITIES into
// pair-major emA (float4/lane: labels 2i,2i+1 at par0 then par1) and a
// compact blank stream emB[b*T + t]. One wave per row, no LDS, no barriers.
__global__ __launch_bounds__(256) void emit_kernel(const float* __restrict__ pred,
                                                   const int* __restrict__ target,
                                                   float* __restrict__ emA,
                                                   float* __restrict__ emB,
                                                   int T, int V, int L) {
    int wave = threadIdx.x >> 6;
    int lane = threadIdx.x & 63;
    int row = blockIdx.x * 4 + wave;            // row = b*T + t
    const float* rowp = pred + (size_t)row * V;
    int nq = V >> 2;                            // 250 float4s
    float4 v0, v1, v2, v3;
    const float4 fill = make_float4(-3.0e38f, -3.0e38f, -3.0e38f, -3.0e38f);
    v0 = (lane       < nq) ? ((const float4*)rowp)[lane]       : fill;
    v1 = (lane + 64  < nq) ? ((const float4*)rowp)[lane + 64]  : fill;
    v2 = (lane + 128 < nq) ? ((const float4*)rowp)[lane + 128] : fill;
    v3 = (lane + 192 < nq) ? ((const float4*)rowp)[lane + 192] : fill;
    float lm = fmaxf(fmaxf(fmaxf(v0.x, v0.y), fmaxf(v0.z, v0.w)),
               fmaxf(fmaxf(fmaxf(v1.x, v1.y), fmaxf(v1.z, v1.w)),
               fmaxf(fmaxf(fmaxf(v2.x, v2.y), fmaxf(v2.z, v2.w)),
                     fmaxf(fmaxf(v3.x, v3.y), fmaxf(v3.z, v3.w)))));
    #pragma unroll
    for (int off = 32; off > 0; off >>= 1) lm = fmaxf(lm, __shfl_xor(lm, off));
    float mm = lm * LOG2E;                      // row max in log2 units
    float ls = 0.f;
    if (lane < nq)
        ls += x2(fmaf(v0.x, LOG2E, -mm)) + x2(fmaf(v0.y, LOG2E, -mm))
            + x2(fmaf(v0.z, LOG2E, -mm)) + x2(fmaf(v0.w, LOG2E, -mm));
    if (lane + 64 < nq)
        ls += x2(fmaf(v1.x, LOG2E, -mm)) + x2(fmaf(v1.y, LOG2E, -mm))
            + x2(fmaf(v1.z, LOG2E, -mm)) + x2(fmaf(v1.w, LOG2E, -mm));
    if (lane + 128 < nq)
        ls += x2(fmaf(v2.x, LOG2E, -mm)) + x2(fmaf(v2.y, LOG2E, -mm))
            + x2(fmaf(v2.z, LOG2E, -mm)) + x2(fmaf(v2.w, LOG2E, -mm));
    if (lane + 192 < nq)
        ls += x2(fmaf(v3.x, LOG2E, -mm)) + x2(fmaf(v3.y, LOG2E, -mm))
            + x2(fmaf(v3.z, LOG2E, -mm)) + x2(fmaf(v3.w, LOG2E, -mm));
    #pragma unroll
    for (int off = 32; off > 0; off >>= 1) ls += __shfl_xor(ls, off);
    float n2 = mm + lg2(ls);                    // log2 normalizer

    int b = row / T;
    int t = row - b * T;
    int p = t >> 1, par = t & 1;
    const int* tg = target + b * L;
    float* arow = emA + ((size_t)b * (T >> 1) + p) * 256;
    for (int j = lane; j < L; j += 64) {
        int tok = tg[j];
        arow[(j >> 1) * 4 + par * 2 + (j & 1)] = x2(fmaf(rowp[tok], LOG2E, -n2));
    }
    float blank_logit = __shfl(v0.x, 0);        // pred[row][0] (token 0)
    if (lane == 0) emB[row] = x2(fmaf(blank_logit, LOG2E, -n2));
}

// Per-batch-element DP state: stored = true * 2^K per lane (linear domain
// with per-lane block exponent).
struct DP {
    float a0, a1, a2, a3;   // 4 extended-label states per lane
    float s1;               // state s=1 (first blank)
    float star_st;          // start-star stored value (lane 0 only)
    float S;                // running sum of alpha_t[ll]+alpha_t[lb]
    float sbase;            // 1.0 on lane 0 else 0
    int   K;                // block exponent
    bool  act;              // lane has been reached
    bool  skipAn;           // right neighbor's skip flag
    bool  skipB;            // within-lane skip (s+2 path)
    bool  slot0;            // ll,lb live in (a0,a1) vs (a2,a3)
    int   lane_e;           // lane holding ll,lb
};

// TWO DP steps (one per element), MANUALLY interleaved statement-by-
// statement. CDNA issue is in-order and the compiler does not interleave
// the chains itself (R2 measured 5.5 cy/instr = fully serial source order);
// alternating the two independent chains in source gives every instruction
// ~2 slots of separation from its producer, hiding dependent-issue latency.
__device__ __forceinline__ void dp_step2(DP& c, DP& e,
                                         float cex0, float cex1, float ceb,
                                         float eex0, float eex1, float eeb,
                                         bool l0) {
    float r0 = c.a3 + c.a2;              float r1 = e.a3 + e.a2;
    float q0 = c.a1 + c.a0;              float q1 = e.a1 + e.a0;
    float w0 = c.skipAn ? r0 : c.a3;     float w1 = e.skipAn ? r1 : e.a3;
    float ur0 = dpp_shr1_f(w0);          float ur1 = dpp_shr1_f(w1);
    int   Kp0 = dpp_shr1_i(c.K);         int   Kp1 = dpp_shr1_i(e.K);
    c.K = c.act ? c.K : Kp0;             e.K = e.act ? e.K : Kp1;
    float uc0 = ldexpf(ur0, c.K - Kp0);  float uc1 = ldexpf(ur1, e.K - Kp1);
    float sb0 = c.s1 + c.star_st;        float sb1 = e.s1 + e.star_st;
    if (l0) { uc0 = sb0; uc1 = sb1; }
    c.S += c.slot0 ? q0 : r0;            e.S += e.slot0 ? q1 : r1;
    float y0 = c.skipB ? q0 : c.a1;      float y1 = e.skipB ? q1 : e.a1;
    c.a2 = cex1 * (c.a2 + y0);           e.a2 = eex1 * (e.a2 + y1);
    c.a0 = cex0 * (c.a0 + uc0);          e.a0 = eex0 * (e.a0 + uc1);
    c.a1 = ceb * q0;                     e.a1 = eeb * q1;
    c.a3 = ceb * r0;                     e.a3 = eeb * r1;
    c.s1 = ceb * sb0;                    e.s1 = eeb * sb1;
    c.act = c.act || (uc0 > 0.0f);       e.act = e.act || (uc1 > 0.0f);
}

// Interleaved per-lane renorm for both elements.
__device__ __forceinline__ void dp_renorm2(DP& c, DP& e) {
    float m0 = fmaxf(fmaxf(c.a0, c.a1), fmaxf(c.a2, c.a3));
    float m1 = fmaxf(fmaxf(e.a0, e.a1), fmaxf(e.a2, e.a3));
    int e0 = (int)((__float_as_uint(m0) >> 23) & 255u) - 127;
    int e1 = (int)((__float_as_uint(m1) >> 23) & 255u) - 127;
    int d0 = c.act ? -e0 : 0;            int d1 = e.act ? -e1 : 0;
    float s0 = ldexpf(1.0f, d0);         float s1_ = ldexpf(1.0f, d1);
    c.a0 *= s0; e.a0 *= s1_;
    c.a1 *= s0; e.a1 *= s1_;
    c.a2 *= s0; e.a2 *= s1_;
    c.a3 *= s0; e.a3 *= s1_;
    c.s1 *= s0; e.s1 *= s1_;
    c.S  *= s0; e.S  *= s1_;
    c.K += d0;                            e.K += d1;
    c.star_st = ldexpf(c.sbase, c.K);    e.star_st = ldexpf(e.sbase, e.K);
}

#define BATCH 12   // pairs per LDS staging batch PER batch-element

// Phase 2: barrier-free single-wave W-CTC DP, TWO batch elements per wave
// with statement-level manual interleave (see dp_step2). Emissions double-
// buffered in LDS via global_load_lds with COUNTED vmcnt(26) waits (one
// 26-load batch-group stays in flight; never a fresh-issue drain).
__global__ __launch_bounds__(64, 1) void dp_kernel(const float* __restrict__ emA,
                                                   const float* __restrict__ emB,
                                                   const int* __restrict__ target,
                                                   const int* __restrict__ tlen,
                                                   float* __restrict__ nll,
                                                   int T, int L, int B) {
    __shared__ float4 sA[2][2][BATCH][64];   // [buf][bi][pair][lane] 49152 B
    __shared__ float  sB[2][2][64];          // [buf][bi][..] blank rows

    int lane = threadIdx.x;
    bool l0 = (lane == 0);
    int b0 = blockIdx.x * 2;
    int b1i = b0 + 1;
    int b1 = (b1i < B) ? b1i : b0;           // clamp (B is even in practice)
    int NP = T >> 1;
    int NPm1 = NP - 1;
    const float* eA0 = emA + (size_t)b0 * NP * 256;
    const float* eA1 = emA + (size_t)b1 * NP * 256;
    const float* eB0 = emB + (size_t)b0 * T;
    const float* eB1 = emB + (size_t)b1 * T;
    const int* tg0 = target + b0 * L;
    const int* tg1 = target + b1 * L;

    int NPc = NP - 1;                        // pairs 1..NP-1 are staged
    int NB = (NPc + BATCH - 1) / BATCH;

    // ---- prologue scalar loads FIRST (so their waits don't drain batches)
    float4 p0a = ((const float4*)eA0)[lane];
    float4 p0b = ((const float4*)eA1)[lane];
    float be0a = eB0[0], be1a = eB0[1];
    float be0b = eB1[0], be1b = eB1[1];
    int t0a = tg0[2 * lane], t1a = tg0[2 * lane + 1];
    int t0b = tg1[2 * lane], t1b = tg1[2 * lane + 1];
    int tla = tlen[b0], tlb = tlen[b1];

    // issue one batch-group (BATCH pair-rows + 1 blank row, both elements)
    // = 26 vmem loads. ALWAYS 26, so counted vmcnt stays valid; indices
    // clamp so dummy tail issues re-read the last rows (target buf is dead).
    #define ISSUE(c, buf)                                                  \
      do {                                                                 \
        int base_ = 1 + BATCH * (c);                                       \
        _Pragma("unroll")                                                  \
        for (int j_ = 0; j_ < BATCH; ++j_) {                               \
            int pr_ = base_ + j_; if (pr_ > NPm1) pr_ = NPm1;              \
            GLLDS(eA0 + (size_t)pr_ * 256, &sA[buf][0][j_][0], 16);        \
            GLLDS(eA1 + (size_t)pr_ * 256, &sA[buf][1][j_][0], 16);        \
        }                                                                  \
        int bb_ = base_ * 2; if (bb_ > T - 1) bb_ = T - 1;                 \
        GLLDS(eB0 + bb_, &sB[buf][0][0], 4);                               \
        GLLDS(eB1 + bb_, &sB[buf][1][0], 4);                               \
      } while (0)

    ISSUE(0, 0);
    ISSUE(1, 1);

    // ---- per-element init
    DP d0, d1;
    {
        int tprev = __shfl_up(t1a, 1);
        bool skipA = (lane == 0) || (t0a != tprev);
        d0.skipAn = (__shfl_down((int)skipA, 1) != 0);
        d0.skipB = (t1a != t0a);
        int ll = 2 * tla;
        d0.lane_e = (ll - 2) >> 2;
        d0.slot0 = ((ll - 2) & 3) == 0;
        d0.a0 = l0 ? p0a.x : 0.f;
        d0.a1 = 0.f; d0.a2 = 0.f; d0.a3 = 0.f;
        d0.s1 = l0 ? be0a : 0.f;
        d0.sbase = l0 ? 1.0f : 0.0f;
        d0.K = 0; d0.star_st = d0.sbase; d0.act = l0; d0.S = 0.f;
    }
    {
        int tprev = __shfl_up(t1b, 1);
        bool skipA = (lane == 0) || (t0b != tprev);
        d1.skipAn = (__shfl_down((int)skipA, 1) != 0);
        d1.skipB = (t1b != t0b);
        int ll = 2 * tlb;
        d1.lane_e = (ll - 2) >> 2;
        d1.slot0 = ((ll - 2) & 3) == 0;
        d1.a0 = l0 ? p0b.x : 0.f;
        d1.a1 = 0.f; d1.a2 = 0.f; d1.a3 = 0.f;
        d1.s1 = l0 ? be0b : 0.f;
        d1.sbase = l0 ? 1.0f : 0.0f;
        d1.K = 0; d1.star_st = d1.sbase; d1.act = l0; d1.S = 0.f;
    }

    // step t=1 from pair 0, parity 1 (both elements, interleaved)
    dp_step2(d0, d1, p0a.z, p0a.w, be1a, p0b.z, p0b.w, be1b, l0);

    for (int c = 0; c < NB; ++c) {
        // batch c resident when only the one in-flight group (26) remains
        asm volatile("s_waitcnt vmcnt(26)" ::: "memory");
        int buf = c & 1;
        int jn = NPc - BATCH * c; if (jn > BATCH) jn = BATCH;
        float4 e0a = sA[buf][0][0][lane], e0b = sA[buf][1][0][lane];
        float2 h0a = *(const float2*)&sB[buf][0][0];
        float2 h0b = *(const float2*)&sB[buf][1][0];
        float4 e1a = sA[buf][0][1][lane], e1b = sA[buf][1][1][lane];
        float2 h1a = *(const float2*)&sB[buf][0][2];
        float2 h1b = *(const float2*)&sB[buf][1][2];
        for (int j = 0; j < jn; ++j) {
            int j2 = j + 2; if (j2 >= BATCH) j2 -= BATCH;
            float4 e2a = sA[buf][0][j2][lane], e2b = sA[buf][1][j2][lane];
            float2 h2a = *(const float2*)&sB[buf][0][2 * j2];
            float2 h2b = *(const float2*)&sB[buf][1][2 * j2];
            dp_step2(d0, d1, e0a.x, e0a.y, h0a.x, e0b.x, e0b.y, h0b.x, l0);
            dp_step2(d0, d1, e0a.z, e0a.w, h0a.y, e0b.z, e0b.w, h0b.y, l0);
            if (j & 1) dp_renorm2(d0, d1);
            e0a = e1a; h0a = h1a; e1a = e2a; h1a = h2a;
            e0b = e1b; h0b = h1b; e1b = e2b; h1b = h2b;
        }
        ISSUE(c + 2, buf);   // always issue (clamped) — keeps vmcnt(26) exact
    }
    #undef ISSUE
    // drain dummy tail issues before LDS teardown at s_endpgm
    asm volatile("s_waitcnt vmcnt(0)" ::: "memory");

    {   // final alpha_{T-1}[ll],[lb] contributions
        float q = d0.a1 + d0.a0, r = d0.a3 + d0.a2;
        d0.S += d0.slot0 ? q : r;
        q = d1.a1 + d1.a0; r = d1.a3 + d1.a2;
        d1.S += d1.slot0 ? q : r;
    }
    float Sv0 = __shfl(d0.S, d0.lane_e);
    int   Kv0 = __shfl(d0.K, d0.lane_e);
    float Sv1 = __shfl(d1.S, d1.lane_e);
    int   Kv1 = __shfl(d1.K, d1.lane_e);
    if (lane == 0) {
        nll[b0] = -((lg2(Sv0) - (float)Kv0) * LN2);
        if (b1i < B) nll[b1i] = -((lg2(Sv1) - (float)Kv1) * LN2);
    }
}

// Phase 3: out = mean_b( nll[b] / tlen[b] )
__global__ __launch_bounds__(64) void fin_kernel(const float* __restrict__ nll,
                                                 const int* __restrict__ tlen,
                                                 float* __restrict__ out, int B) {
    int tid = threadIdx.x;
    float v = (tid < B) ? nll[tid] / (float)tlen[tid] : 0.f;
    #pragma unroll
    for (int off = 32; off > 0; off >>= 1) v += __shfl_xor(v, off);
    if (tid == 0) out[0] = v / (float)B;
}

extern "C" void kernel_launch(void* const* d_in, const int* in_sizes, int n_in,
                              void* d_out, int out_size, void* d_ws, size_t ws_size,
                              hipStream_t stream) {
    const float* pred   = (const float*)d_in[0];
    const int*   target = (const int*)d_in[1];
    const int*   tlen   = (const int*)d_in[2];
    int B = in_sizes[2];
    int L = in_sizes[1] / B;            // 128
    int V = 1000;                       // fixed by the problem
    int T = in_sizes[0] / (B * V);      // 1024

    float* ws  = (float*)d_ws;
    float* nll = ws;                    // 64 floats
    float* emB = ws + 64;               // B*T floats (blank probs, compact)
    float* emA = emB + (size_t)B * T;   // B*(T/2)*256 floats (~16.8 MB)
                                        // (emB precedes emA so the blank
                                        // batch-load's 64-lane over-read on
                                        // the last batch stays inside ws)

    emit_kernel<<<(B * T) / 4, 256, 0, stream>>>(pred, target, emA, emB, T, V, L);
    dp_kernel<<<(B + 1) / 2, 64, 0, stream>>>(emA, emB, target, tlen, nll, T, L, B);
    fin_kernel<<<1, 64, 0, stream>>>(nll, tlen, (float*)d_out, B);
}

// Round 6
// 264.842 us; speedup vs baseline: 1.3721x; 1.3678x over previous
//
#include <hip/hip_runtime.h>

#define LOG2E 1.4426950408889634f
#define LN2   0.6931471805599453f

__device__ __forceinline__ float x2(float x)  { return __builtin_amdgcn_exp2f(x); }
__device__ __forceinline__ float lg2(float x) { return __builtin_amdgcn_logf(x); }

// DPP wave_shr:1 — lane i <- lane i-1, VALU-local (no LDS pipe, no lgkmcnt).
// Lane 0 gets 0 (old operand); callers never consume lane 0's result.
__device__ __forceinline__ float dpp_shr1_f(float x) {
    return __int_as_float(
        __builtin_amdgcn_update_dpp(0, __float_as_int(x), 0x138, 0xf, 0xf, false));
}
__device__ __forceinline__ int dpp_shr1_i(int x) {
    return __builtin_amdgcn_update_dpp(0, x, 0x138, 0xf, 0xf, false);
}

// async global->LDS DMA (wave-uniform base, lane*size scatter)
#define GLLDS(g, l, sz)                                                    \
    __builtin_amdgcn_global_load_lds(                                      \
        (const __attribute__((address_space(1))) void*)(g),                \
        (__attribute__((address_space(3))) void*)(l), (sz), 0, 0)

// Phase 1: per-(b,t) softmax normalizer + gather token PROBABILITIES into
// pair-major emA (float4/lane: labels 2i,2i+1 at par0 then par1) and a
// compact blank stream emB[b*T + t]. One wave per row, no LDS, no barriers.
__global__ __launch_bounds__(256) void emit_kernel(const float* __restrict__ pred,
                                                   const int* __restrict__ target,
                                                   float* __restrict__ emA,
                                                   float* __restrict__ emB,
                                                   int T, int V, int L) {
    int wave = threadIdx.x >> 6;
    int lane = threadIdx.x & 63;
    int row = blockIdx.x * 4 + wave;            // row = b*T + t
    const float* rowp = pred + (size_t)row * V;
    int nq = V >> 2;                            // 250 float4s
    float4 v0, v1, v2, v3;
    const float4 fill = make_float4(-3.0e38f, -3.0e38f, -3.0e38f, -3.0e38f);
    v0 = (lane       < nq) ? ((const float4*)rowp)[lane]       : fill;
    v1 = (lane + 64  < nq) ? ((const float4*)rowp)[lane + 64]  : fill;
    v2 = (lane + 128 < nq) ? ((const float4*)rowp)[lane + 128] : fill;
    v3 = (lane + 192 < nq) ? ((const float4*)rowp)[lane + 192] : fill;
    float lm = fmaxf(fmaxf(fmaxf(v0.x, v0.y), fmaxf(v0.z, v0.w)),
               fmaxf(fmaxf(fmaxf(v1.x, v1.y), fmaxf(v1.z, v1.w)),
               fmaxf(fmaxf(fmaxf(v2.x, v2.y), fmaxf(v2.z, v2.w)),
                     fmaxf(fmaxf(v3.x, v3.y), fmaxf(v3.z, v3.w)))));
    #pragma unroll
    for (int off = 32; off > 0; off >>= 1) lm = fmaxf(lm, __shfl_xor(lm, off));
    float mm = lm * LOG2E;                      // row max in log2 units
    float ls = 0.f;
    if (lane < nq)
        ls += x2(fmaf(v0.x, LOG2E, -mm)) + x2(fmaf(v0.y, LOG2E, -mm))
            + x2(fmaf(v0.z, LOG2E, -mm)) + x2(fmaf(v0.w, LOG2E, -mm));
    if (lane + 64 < nq)
        ls += x2(fmaf(v1.x, LOG2E, -mm)) + x2(fmaf(v1.y, LOG2E, -mm))
            + x2(fmaf(v1.z, LOG2E, -mm)) + x2(fmaf(v1.w, LOG2E, -mm));
    if (lane + 128 < nq)
        ls += x2(fmaf(v2.x, LOG2E, -mm)) + x2(fmaf(v2.y, LOG2E, -mm))
            + x2(fmaf(v2.z, LOG2E, -mm)) + x2(fmaf(v2.w, LOG2E, -mm));
    if (lane + 192 < nq)
        ls += x2(fmaf(v3.x, LOG2E, -mm)) + x2(fmaf(v3.y, LOG2E, -mm))
            + x2(fmaf(v3.z, LOG2E, -mm)) + x2(fmaf(v3.w, LOG2E, -mm));
    #pragma unroll
    for (int off = 32; off > 0; off >>= 1) ls += __shfl_xor(ls, off);
    float n2 = mm + lg2(ls);                    // log2 normalizer

    int b = row / T;
    int t = row - b * T;
    int p = t >> 1, par = t & 1;
    const int* tg = target + b * L;
    float* arow = emA + ((size_t)b * (T >> 1) + p) * 256;
    for (int j = lane; j < L; j += 64) {
        int tok = tg[j];
        arow[(j >> 1) * 4 + par * 2 + (j & 1)] = x2(fmaf(rowp[tok], LOG2E, -n2));
    }
    float blank_logit = __shfl(v0.x, 0);        // pred[row][0] (token 0)
    if (lane == 0) emB[row] = x2(fmaf(blank_logit, LOG2E, -n2));
}

// One linear-domain DP state update (R1-verbatim). stored = true * 2^K per
// lane; left-neighbor value re-framed by ldexp(K-Kp); neighbor pre-selects
// what this lane needs (skipAn) -> 2 DPP wave_shr1. Zero transcendentals.
#define STEP_CORE(EX0, EX1, EB)                                           \
  do {                                                                    \
    float r  = a3 + a2;                                                   \
    float q  = a1 + a0;                                                   \
    float w  = skipAn ? r : a3;     /* value my RIGHT neighbor needs */   \
    float ur = dpp_shr1_f(w);                                             \
    int   Kp = dpp_shr1_i(K);                                             \
    K = act ? K : Kp;                                                     \
    float uc = ldexpf(ur, K - Kp);                                        \
    float sb = s1 + star_st;                                              \
    if (lane == 0) uc = sb;                                               \
    S += slot0 ? q : r;                                                   \
    a2 = (EX1) * (a2 + (skipB ? q : a1));                                 \
    a0 = (EX0) * (a0 + uc);                                               \
    a1 = (EB) * q;                                                        \
    a3 = (EB) * r;                                                        \
    s1 = (EB) * sb;                                                       \
    act = act || (uc > 0.0f);                                             \
  } while (0)

// Per-lane renorm (R1-verbatim): rescale stored so lane max ~ 1, fold into K.
#define RENORM                                                            \
  do {                                                                    \
    float m4 = fmaxf(fmaxf(a0, a1), fmaxf(a2, a3));                       \
    int e = (int)((__float_as_uint(m4) >> 23) & 255u) - 127;              \
    int d = act ? -e : 0;                                                 \
    float sc = ldexpf(1.0f, d);                                           \
    a0 *= sc; a1 *= sc; a2 *= sc; a3 *= sc; s1 *= sc; S *= sc;            \
    K += d;                                                               \
    star_st = ldexpf(sbase, K);                                           \
  } while (0)

#define BATCH 24   // pairs per LDS staging batch (48 timesteps of cover)

// Phase 2: barrier-free single-wave W-CTC DP, LINEAR domain with per-lane
// block exponents. R1 body + (a) FULL UNROLL of the 24-pair batch (kills
// the 6 rotation movs/step; LDS reads become compile-time offsets) and
// (b) COUNTED vmcnt(25) waits (R3/R4-proven pattern: the waited batch was
// issued two consume-phases earlier -> no HBM-latency drain per batch,
// unlike R1's vmcnt(0) which drained the just-issued prefetch).
__global__ __launch_bounds__(64, 1) void dp_kernel(const float* __restrict__ emA,
                                                   const float* __restrict__ emB,
                                                   const int* __restrict__ target,
                                                   const int* __restrict__ tlen,
                                                   float* __restrict__ nll,
                                                   int T, int L) {
    __shared__ float4 sA[2][BATCH][64];   // 49152 B
    __shared__ float  sB[2][64];          // 512 B (blank rows, 64-f padded)

    int b = blockIdx.x;
    int lane = threadIdx.x;
    int NP = T >> 1;
    int NPm1 = NP - 1;
    const float* eAb = emA + (size_t)b * NP * 256;
    const float* eBb = emB + (size_t)b * T;
    const int* tg = target + b * L;

    int NPc = NP - 1;                     // pairs 1..NP-1 are staged
    int full = NPc / BATCH;               // full batches (21 at T=1024)
    int tail = NPc % BATCH;               // leftover pairs (7)

    // issue one batch (BATCH pair-rows + 1 blank row) = 25 loads into buf.
    // ALWAYS 25 (clamped dummies on overrun) so counted vmcnt stays exact.
    #define ISSUE(c, buf)                                                  \
      do {                                                                 \
        int base_ = 1 + BATCH * (c);                                       \
        _Pragma("unroll")                                                  \
        for (int j_ = 0; j_ < BATCH; ++j_) {                               \
            int pr_ = base_ + j_; if (pr_ > NPm1) pr_ = NPm1;              \
            GLLDS(eAb + (size_t)pr_ * 256, &sA[buf][j_][0], 16);           \
        }                                                                  \
        int bb_ = base_ * 2; if (bb_ > T - 1) bb_ = T - 1;                 \
        GLLDS(eBb + bb_, &sB[buf][0], 4);                                  \
      } while (0)

    ISSUE(0, 0);
    ISSUE(1, 1);

    // pair 0 (t=0 init + t=1 step): direct scalar loads, outside the loop
    float4 p0 = ((const float4*)eAb)[lane];
    float be0 = eBb[0], be1 = eBb[1];

    int t0 = tg[2 * lane];
    int t1 = tg[2 * lane + 1];
    int tprev = __shfl_up(t1, 1);                // garbage on lane 0 (unused)
    bool skipA = (lane == 0) || (t0 != tprev);
    bool skipAn = (__shfl_down((int)skipA, 1) != 0);  // right neighbor's skipA
    bool skipB = (t1 != t0);

    int tl = tlen[b];
    int ll = 2 * tl;
    int lane_e = (ll - 2) >> 2;
    bool slot0 = ((ll - 2) & 3) == 0;            // ll,lb in (a0,a1) vs (a2,a3)

    // t=0 init (linear): star=1 (lane0), s=1 -> blank prob, s=2 -> label0 prob
    float a0 = (lane == 0) ? p0.x : 0.f;
    float a1 = 0.f, a2 = 0.f, a3 = 0.f;
    float s1 = (lane == 0) ? be0 : 0.f;
    float sbase = (lane == 0) ? 1.0f : 0.0f;
    int   K = 0;
    float star_st = sbase;                       // star stored = 1 * 2^K (lane 0)
    bool  act = (lane == 0);
    float S = 0.f;                               // running sum of alpha_t[ll]+[lb]

    // step t=1 from pair 0, parity 1
    STEP_CORE(p0.z, p0.w, be1);

    for (int c = 0; c < full; ++c) {
        // batch c resident when only the one in-flight batch (25) remains;
        // batch c was issued two consume-phases ago -> no stall here.
        asm volatile("s_waitcnt vmcnt(25)" ::: "memory");
        int buf = c & 1;
        const float4 (*sAb)[64] = sA[buf];
        const float* sBb = sB[buf];
        #pragma unroll
        for (int j = 0; j < BATCH; ++j) {
            float4 e4 = sAb[j][lane];
            float2 b2 = *(const float2*)&sBb[2 * j];
            STEP_CORE(e4.x, e4.y, b2.x);
            STEP_CORE(e4.z, e4.w, b2.y);
            if (j & 1) RENORM;
        }
        ISSUE(c + 2, buf);   // always issue (clamped) — keeps vmcnt exact
    }
    if (tail) {
        asm volatile("s_waitcnt vmcnt(0)" ::: "memory");
        int buf = full & 1;
        for (int j = 0; j < tail; ++j) {
            float4 e4 = sA[buf][j][lane];
            float2 b2 = *(const float2*)&sB[buf][2 * j];
            STEP_CORE(e4.x, e4.y, b2.x);
            STEP_CORE(e4.z, e4.w, b2.y);
            if (j & 1) RENORM;
        }
    }
    #undef ISSUE
    // drain clamped dummy issues before LDS teardown at s_endpgm
    asm volatile("s_waitcnt vmcnt(0)" ::: "memory");

    {   // final alpha_{T-1}[ll],[lb] contribution
        float q = a1 + a0;
        float r = a3 + a2;
        S += slot0 ? q : r;
    }
    float Sv = __shfl(S, lane_e);
    int   Kv = __shfl(K, lane_e);
    if (lane == 0) nll[b] = -((lg2(Sv) - (float)Kv) * LN2);   // back to nats
}

// Phase 3: out = mean_b( nll[b] / tlen[b] )
__global__ __launch_bounds__(64) void fin_kernel(const float* __restrict__ nll,
                                                 const int* __restrict__ tlen,
                                                 float* __restrict__ out, int B) {
    int tid = threadIdx.x;
    float v = (tid < B) ? nll[tid] / (float)tlen[tid] : 0.f;
    #pragma unroll
    for (int off = 32; off > 0; off >>= 1) v += __shfl_xor(v, off);
    if (tid == 0) out[0] = v / (float)B;
}

extern "C" void kernel_launch(void* const* d_in, const int* in_sizes, int n_in,
                              void* d_out, int out_size, void* d_ws, size_t ws_size,
                              hipStream_t stream) {
    const float* pred   = (const float*)d_in[0];
    const int*   target = (const int*)d_in[1];
    const int*   tlen   = (const int*)d_in[2];
    int B = in_sizes[2];
    int L = in_sizes[1] / B;            // 128
    int V = 1000;                       // fixed by the problem
    int T = in_sizes[0] / (B * V);      // 1024

    float* ws  = (float*)d_ws;
    float* nll = ws;                    // 64 floats
    float* emB = ws + 64;               // B*T floats (blank probs, compact)
    float* emA = emB + (size_t)B * T;   // B*(T/2)*256 floats (~16.8 MB)
                                        // (emB precedes emA so the blank
                                        // batch-load's 64-lane over-read on
                                        // the last batch stays inside ws)

    emit_kernel<<<(B * T) / 4, 256, 0, stream>>>(pred, target, emA, emB, T, V, L);
    dp_kernel<<<B, 64, 0, stream>>>(emA, emB, target, tlen, nll, T, L);
    fin_kernel<<<1, 64, 0, stream>>>(nll, tlen, (float*)d_out, B);
}